// Round 23
// baseline (350.531 us; speedup 1.0000x reference)
//
#include <hip/hip_runtime.h>

#define NN 100000   // real nodes
#define NP 100096   // padded to 782*128
#define NE 600000   // edges
#define CC 128      // channels

typedef __attribute__((ext_vector_type(4))) float f32x4;
typedef _Float16 h8 __attribute__((ext_vector_type(8)));
typedef _Float16 h2 __attribute__((ext_vector_type(2)));

// H-region LDS granule perm (bijective per row)
__device__ __forceinline__ int pg(int R, int g) {
  return g ^ (R & 7) ^ (((R >> 2) & 3) << 1);
}

#define DC_INT4 ((NP + NN) / 4)

__global__ void k_zero(int4* __restrict__ dst) {
  int i = blockIdx.x * 256 + threadIdx.x;
  if (i < DC_INT4) dst[i] = make_int4(0, 0, 0, 0);
}

// ---------------- graph preprocessing ----------------

__global__ void k_deg(const int* __restrict__ col, int* __restrict__ deg) {
  int e = blockIdx.x * 256 + threadIdx.x;
  if (e < NE) atomicAdd(&deg[col[e]], 1);
}

__global__ void k_scan1(const int* __restrict__ deg, int* __restrict__ rowptr,
                        int* __restrict__ bsum, float* __restrict__ dis) {
  __shared__ int s[1024];
  int t = threadIdx.x;
  int i = blockIdx.x * 1024 + t;
  int v = (i < NN) ? deg[i] : 0;
  if (i < NN) dis[i] = (v > 0) ? rsqrtf((float)v) : 0.0f;
  s[t] = v;
  __syncthreads();
  #pragma unroll
  for (int off = 1; off < 1024; off <<= 1) {
    int tv = (t >= off) ? s[t - off] : 0;
    __syncthreads();
    s[t] += tv;
    __syncthreads();
  }
  if (i < NN) rowptr[i] = s[t] - v;           // exclusive
  if (t == 1023) bsum[blockIdx.x] = s[1023];
}

__global__ void k_scan2(const int* __restrict__ bsum, int* __restrict__ bsum2,
                        int* __restrict__ rowptr) {
  int t = threadIdx.x;
  if (t < NP + 8 - NN) rowptr[NN + t] = NE;   // 104 entries
  __shared__ int s[128];
  int v = (t < 98) ? bsum[t] : 0;
  s[t] = v;
  __syncthreads();
  #pragma unroll
  for (int off = 1; off < 128; off <<= 1) {
    int tv = (t >= off) ? s[t - off] : 0;
    __syncthreads();
    s[t] += tv;
    __syncthreads();
  }
  bsum2[t] = s[t] - v;                        // exclusive
}

__global__ void k_scan3(int* __restrict__ rowptr, const int* __restrict__ bsum2) {
  int i = blockIdx.x * 1024 + threadIdx.x;
  if (i < NN) rowptr[i] += bsum2[blockIdx.x];
}

__global__ void k_fill(const int* __restrict__ row, const int* __restrict__ col,
                       const float* __restrict__ dis, const int* __restrict__ rowptr,
                       int* __restrict__ cnt, int2* __restrict__ csr) {
  int e = blockIdx.x * 256 + threadIdx.x;
  if (e >= NE) return;
  int c = col[e], r = row[e];
  int pos = rowptr[c] + atomicAdd(&cnt[c], 1);
  int2 v;
  v.x = r * CC;
  v.y = __float_as_int(dis[r] * dis[c]);
  csr[pos] = v;
}

// ---------------- lin0 ----------------

__global__ void k_lin0(const float* __restrict__ x, const float* __restrict__ W0,
                       const float* __restrict__ b0, _Float16* __restrict__ h) {
  int idx = blockIdx.x * 256 + threadIdx.x;   // n*128 + c
  int n = idx >> 7, c = idx & 127;
  if (n >= NP) return;
  float v = 0.0f;
  if (n < NN) {
    v = b0[c];
    #pragma unroll
    for (int f = 0; f < 6; ++f) v = fmaf(x[n * 6 + f], W0[f * CC + c], v);
    v = fmaxf(v, 0.0f);
  }
  h[idx] = (_Float16)v;
}

// ---------------- W conversion ----------------

__global__ void k_wconv2(const float* __restrict__ srcT, const float* __restrict__ srcM,
                         _Float16* __restrict__ dst) {
  int tid0 = blockIdx.x * 256 + threadIdx.x;
  if (tid0 >= 1280 * 128) return;
  const float* src = srcT;
  int tid = tid0;
  if (tid0 >= 1024 * 128) { src = srcM; tid = tid0 - 1024 * 128; }
  int e = tid & 7, l = (tid >> 3) & 63, nb = (tid >> 9) & 7, kb = tid >> 12;
  int k = kb * 32 + (l >> 4) * 8 + e;
  int c = nb * 16 + (l & 15);
  dst[tid0] = (_Float16)src[k * 128 + c];
}

// ---------------- propagation (r10 variant; at random-gather fabric ceiling) ----

__global__ __launch_bounds__(256) void k_prop(const int* __restrict__ rowptr,
                                              const int2* __restrict__ csr,
                                              const _Float16* __restrict__ xin,
                                              _Float16* __restrict__ xout) {
  int gid = blockIdx.x * 256 + threadIdx.x;
  int wv = gid >> 6;
  int lane = gid & 63;
  int n0 = wv * 4;
  if (n0 >= NP) return;
  int b0 = rowptr[n0], b1 = rowptr[n0 + 1], b2 = rowptr[n0 + 2],
      b3 = rowptr[n0 + 3], b4 = rowptr[n0 + 4];
  int e4 = b4 - b0;

  int2 ew; ew.x = 0; ew.y = 0;
  int gl = 0;
  if (lane < e4) {
    int pos = b0 + lane;
    ew = csr[pos];
    gl = (pos >= b1) + (pos >= b2) + (pos >= b3);
  }

  float a00 = 0, a01 = 0, a10 = 0, a11 = 0, a20 = 0, a21 = 0, a30 = 0, a31 = 0;
  int nb = e4 < 64 ? e4 : 64;
  for (int j = 0; j < nb; j += 8) {
    #pragma unroll
    for (int u = 0; u < 8; ++u) {
      int off = __shfl(ew.x, j + u);
      float w = __uint_as_float(__shfl(ew.y, j + u));
      int gg = __shfl(gl, j + u);
      h2 v = *reinterpret_cast<const h2*>(&xin[off + lane * 2]);
      float v0 = (float)v[0], v1 = (float)v[1];
      float w0 = (gg == 0) ? w : 0.0f;
      float w1 = (gg == 1) ? w : 0.0f;
      float w2 = (gg == 2) ? w : 0.0f;
      float w3 = (gg == 3) ? w : 0.0f;
      a00 += w0 * v0; a01 += w0 * v1;
      a10 += w1 * v0; a11 += w1 * v1;
      a20 += w2 * v0; a21 += w2 * v1;
      a30 += w3 * v0; a31 += w3 * v1;
    }
  }
  for (int j = 64; j < e4; ++j) {
    int pos = b0 + j;
    int2 e2 = csr[pos];
    float w = __uint_as_float(e2.y);
    int gg = (pos >= b1) + (pos >= b2) + (pos >= b3);
    h2 v = *reinterpret_cast<const h2*>(&xin[e2.x + lane * 2]);
    float v0 = (float)v[0], v1 = (float)v[1];
    float w0 = (gg == 0) ? w : 0.0f;
    float w1 = (gg == 1) ? w : 0.0f;
    float w2 = (gg == 2) ? w : 0.0f;
    float w3 = (gg == 3) ? w : 0.0f;
    a00 += w0 * v0; a01 += w0 * v1;
    a10 += w1 * v0; a11 += w1 * v1;
    a20 += w2 * v0; a21 += w2 * v1;
    a30 += w3 * v0; a31 += w3 * v1;
  }

  h2 o;
  o[0] = (_Float16)a00; o[1] = (_Float16)a01;
  *reinterpret_cast<h2*>(&xout[(size_t)(n0 + 0) * CC + lane * 2]) = o;
  o[0] = (_Float16)a10; o[1] = (_Float16)a11;
  *reinterpret_cast<h2*>(&xout[(size_t)(n0 + 1) * CC + lane * 2]) = o;
  o[0] = (_Float16)a20; o[1] = (_Float16)a21;
  *reinterpret_cast<h2*>(&xout[(size_t)(n0 + 2) * CC + lane * 2]) = o;
  o[0] = (_Float16)a30; o[1] = (_Float16)a31;
  *reinterpret_cast<h2*>(&xout[(size_t)(n0 + 3) * CC + lane * 2]) = o;
}

// ---------------- MFMA GEMM: M=64 tile, BK=64 triple-buffer, ONE barrier/chunk ----
// CORRECTED schedule (r22 raced: barrier preceded the per-wave vmcnt, so wave A could
// compute while wave B's stage loads were in flight — tile rows are cross-wave).
// Per chunk c:  vmcnt(2)  [own chunk-c loads retired; c+1's 2 in flight]
//            -> s_barrier [ALL waves' chunk-c writes visible; chunk c-1 reads done]
//            -> stage(c+2) into buf[(c+2)%3]  [last read at chunk c-1: safe]
//            -> compute(c) from buf[c%3]

template<int KB, bool BR>
__global__ __launch_bounds__(256) void k_mm(const _Float16* __restrict__ X0,
                                            const _Float16* __restrict__ X1,
                                            const _Float16* __restrict__ X2,
                                            const _Float16* __restrict__ X3,
                                            const _Float16* __restrict__ Wp,
                                            const float* __restrict__ bias,
                                            _Float16* __restrict__ Y) {
  __shared__ _Float16 lds[3][64 * 64];        // 3 x 8 KB
  int t = threadIdx.x;
  int w = t >> 6, l = t & 63;
  int lr = l & 15, lk = l >> 4;
  int m0w = (w & 1) * 32;
  int nb0 = (w >> 1) * 4;
  long row0 = (long)blockIdx.x * 64;
  const _Float16* Xs[4] = {X0, X1, X2, X3};
  const int CH = KB * 2;                      // chunks of K=64

  auto stage = [&](int buf, int c) {
    const _Float16* __restrict__ xb = Xs[c >> 1];
    int half = c & 1;
    #pragma unroll
    for (int i = 0; i < 2; ++i) {
      int li = i * 256 + t;                   // 16B-granule index 0..511
      int r = li >> 3, ck = li & 7;
      int cs = ck ^ (r & 7);
      const _Float16* src = xb + (size_t)(row0 + r) * CC + half * 64 + cs * 8;
      _Float16* dst = &lds[buf][i * 2048 + (t & 192) * 8];
      __builtin_amdgcn_global_load_lds((const __attribute__((address_space(1))) void*)src,
                                       (__attribute__((address_space(3))) void*)dst,
                                       16, 0, 0);
    }
  };

  f32x4 acc[2][4];
  #pragma unroll
  for (int m = 0; m < 2; ++m)
    #pragma unroll
    for (int n = 0; n < 4; ++n) acc[m][n] = (f32x4){0.f, 0.f, 0.f, 0.f};

  stage(0, 0);
  stage(1, 1);
  #pragma unroll
  for (int c = 0; c < CH; ++c) {
    if (c + 1 < CH) {
      asm volatile("s_waitcnt vmcnt(2)" ::: "memory");   // chunk c retired; c+1 in flight
    } else {
      asm volatile("s_waitcnt vmcnt(0)" ::: "memory");   // last chunk: drain
    }
    __builtin_amdgcn_sched_barrier(0);
    __builtin_amdgcn_s_barrier();             // all waves' chunk-c writes visible; c-1 reads done
    if (c + 2 < CH) stage((c + 2) % 3, c + 2);
    __builtin_amdgcn_sched_barrier(0);
    const _Float16* __restrict__ lb = lds[c % 3];

    #pragma unroll
    for (int kk = 0; kk < 2; ++kk) {
      int kb = c * 2 + kk;
      h8 a[2], b[4];
      #pragma unroll
      for (int m = 0; m < 2; ++m) {
        int R = m0w + m * 16 + lr;
        a[m] = *reinterpret_cast<const h8*>(&lb[R * 64 + (((kk * 4 + lk) ^ (R & 7)) << 3)]);
      }
      #pragma unroll
      for (int n = 0; n < 4; ++n)
        b[n] = *reinterpret_cast<const h8*>(&Wp[((size_t)(kb * 8 + nb0 + n) * 64 + l) * 8]);
      #pragma unroll
      for (int m = 0; m < 2; ++m)
        #pragma unroll
        for (int n = 0; n < 4; ++n)
          acc[m][n] = __builtin_amdgcn_mfma_f32_16x16x32_f16(a[m], b[n], acc[m][n], 0, 0, 0);
    }
  }

  int r0 = m0w + lk * 4;
  long rb = row0 + r0;
  #pragma unroll
  for (int m = 0; m < 2; ++m) {
    #pragma unroll
    for (int n = 0; n < 4; ++n) {
      int c = (nb0 + n) * 16 + lr;
      float bv = BR ? bias[c] : 0.0f;
      #pragma unroll
      for (int q = 0; q < 4; ++q) {
        float v = acc[m][n][q] + bv;
        if (BR) v = fmaxf(v, 0.0f);
        Y[(rb + m * 16 + q) * CC + c] = (_Float16)v;
      }
    }
  }
}

// ---------------- fused tail, M=64 tile (r21 form, known good) ----------------

__global__ __launch_bounds__(256) void k_tail(const _Float16* __restrict__ X,
                                              const _Float16* __restrict__ WpM,
                                              const float* __restrict__ b_mlp,
                                              const float* __restrict__ W1,
                                              const float* __restrict__ b1,
                                              float* __restrict__ out) {
  __shared__ _Float16 lds[64 * 128];          // 16 KB
  int t = threadIdx.x;
  int w = t >> 6, l = t & 63;
  int lr = l & 15, lk = l >> 4;
  int m0w = (w & 1) * 32;
  int nb0 = (w >> 1) * 4;
  long row0 = (long)blockIdx.x * 64;

  #pragma unroll
  for (int i = 0; i < 4; ++i) {
    int li = i * 256 + t;                     // granule 0..1023
    int r = li >> 4, ck = li & 15;
    int cs = ck ^ (r & 7);
    const _Float16* src = X + (size_t)(row0 + r) * CC + cs * 8;
    _Float16* dst = &lds[i * 2048 + (t & 192) * 8];
    __builtin_amdgcn_global_load_lds((const __attribute__((address_space(1))) void*)src,
                                     (__attribute__((address_space(3))) void*)dst,
                                     16, 0, 0);
  }
  __syncthreads();

  f32x4 acc[2][4];
  #pragma unroll
  for (int ph = 0; ph < 2; ++ph) {
    #pragma unroll
    for (int m = 0; m < 2; ++m)
      #pragma unroll
      for (int n = 0; n < 4; ++n) acc[m][n] = (f32x4){0.f, 0.f, 0.f, 0.f};
    #pragma unroll
    for (int kk = 0; kk < 4; ++kk) {
      h8 a[2], b[4];
      #pragma unroll
      for (int m = 0; m < 2; ++m) {
        int R = m0w + m * 16 + lr;
        int g = kk * 4 + lk;
        int gp = (ph == 0) ? (g ^ (R & 7)) : pg(R, g);
        a[m] = *reinterpret_cast<const h8*>(&lds[R * 128 + gp * 8]);
      }
      #pragma unroll
      for (int n = 0; n < 4; ++n)
        b[n] = *reinterpret_cast<const h8*>(&WpM[((size_t)((ph * 4 + kk) * 8 + nb0 + n) * 64 + l) * 8]);
      #pragma unroll
      for (int m = 0; m < 2; ++m)
        #pragma unroll
        for (int n = 0; n < 4; ++n)
          acc[m][n] = __builtin_amdgcn_mfma_f32_16x16x32_f16(a[m], b[n], acc[m][n], 0, 0, 0);
    }
    __syncthreads();
    #pragma unroll
    for (int m = 0; m < 2; ++m) {
      #pragma unroll
      for (int n = 0; n < 4; ++n) {
        int c = (nb0 + n) * 16 + lr;
        float bv = b_mlp[ph * 128 + c];
        int g = c >> 3, eo = c & 7;
        #pragma unroll
        for (int q = 0; q < 4; ++q) {
          int R = m0w + m * 16 + lk * 4 + q;
          float v = fmaxf(acc[m][n][q] + bv, 0.0f);
          lds[R * 128 + pg(R, g) * 8 + eo] = (_Float16)v;
        }
      }
    }
    __syncthreads();
  }

  int gH = l & 15;
  float w1s[8];
  #pragma unroll
  for (int q = 0; q < 8; ++q) w1s[q] = W1[gH * 8 + q];
  float b1v = b1[0];
  #pragma unroll
  for (int ps = 0; ps < 4; ++ps) {
    int R = w * 16 + ps * 4 + (l >> 4);
    h8 hv = *reinterpret_cast<const h8*>(&lds[R * 128 + pg(R, gH) * 8]);
    float s = 0.0f;
    #pragma unroll
    for (int q = 0; q < 8; ++q) s = fmaf((float)hv[q], w1s[q], s);
    s += __shfl_xor(s, 1);
    s += __shfl_xor(s, 2);
    s += __shfl_xor(s, 4);
    s += __shfl_xor(s, 8);
    long grow = row0 + R;
    if (gH == 0 && grow < NN) out[grow] = fmaxf(s + b1v, 0.0f);
  }
}

// ---------------- launch ----------------

extern "C" void kernel_launch(void* const* d_in, const int* in_sizes, int n_in,
                              void* d_out, int out_size, void* d_ws, size_t ws_size,
                              hipStream_t stream) {
  const float* x     = (const float*)d_in[0];
  const int*   ei    = (const int*)d_in[1];
  const float* W0    = (const float*)d_in[2];
  const float* b0    = (const float*)d_in[3];
  const float* W_tag = (const float*)d_in[4];
  const float* b_tag = (const float*)d_in[5];
  const float* W_mlp = (const float*)d_in[6];
  const float* b_mlp = (const float*)d_in[7];
  const float* W1    = (const float*)d_in[8];
  const float* b1    = (const float*)d_in[9];
  const int* row = ei;          // edge_index[0] = source
  const int* col = ei + NE;     // edge_index[1] = target

  char* p = (char*)d_ws;
  auto carve = [&](size_t bytes) { void* r = (void*)p; p += (bytes + 255) & ~(size_t)255; return r; };
  _Float16* hA   = (_Float16*)carve((size_t)NP * CC * 2);
  _Float16* hB   = (_Float16*)carve((size_t)NP * CC * 2);
  _Float16* x1   = (_Float16*)carve((size_t)NP * CC * 2);
  _Float16* x2   = (_Float16*)carve((size_t)NP * CC * 2);
  _Float16* x3   = (_Float16*)carve((size_t)NP * CC * 2);
  _Float16* WpT  = (_Float16*)carve((size_t)1024 * CC * 2);
  _Float16* WpM  = (_Float16*)carve((size_t)256 * CC * 2);
  float* dis     = (float*)carve((size_t)NP * 4);
  int*   dc      = (int*)carve((size_t)(NP + NN) * 4);
  int*   deg     = dc;
  int*   cnt     = dc + NP;
  int*   rowptr  = (int*)carve((size_t)(NP + 8) * 4);
  int*   bsum    = (int*)carve(512);
  int*   bsum2   = (int*)carve(512);
  int2*  csr     = (int2*)carve((size_t)NE * 8);

  k_zero<<<(DC_INT4 + 255) / 256, 256, 0, stream>>>((int4*)dc);

  k_deg<<<(NE + 255) / 256, 256, 0, stream>>>(col, deg);
  k_scan1<<<98, 1024, 0, stream>>>(deg, rowptr, bsum, dis);
  k_scan2<<<1, 128, 0, stream>>>(bsum, bsum2, rowptr);
  k_scan3<<<98, 1024, 0, stream>>>(rowptr, bsum2);
  k_fill<<<(NE + 255) / 256, 256, 0, stream>>>(row, col, dis, rowptr, cnt, csr);

  k_wconv2<<<(1280 * CC + 255) / 256, 256, 0, stream>>>(W_tag, W_mlp, WpT);

  k_lin0<<<NP * CC / 256, 256, 0, stream>>>(x, W0, b0, hA);

  const int GB64 = NP / 64;            // 1564 blocks (M=64 tiles)
  const int PB   = (NP / 4) * 64 / 256;

  _Float16* hc = hA;
  _Float16* hn = hB;
  for (int g = 0; g < 2; ++g) {
    k_prop<<<PB, 256, 0, stream>>>(rowptr, csr, hc, x1);
    k_prop<<<PB, 256, 0, stream>>>(rowptr, csr, x1, x2);
    k_prop<<<PB, 256, 0, stream>>>(rowptr, csr, x2, x3);
    k_mm<4, true><<<GB64, 256, 0, stream>>>(hc, x1, x2, x3, WpT + (size_t)g * 512 * CC,
                                            b_tag + (size_t)g * CC, hn);
    _Float16* tmp = hc; hc = hn; hn = tmp;
  }

  k_tail<<<GB64, 256, 0, stream>>>(hc, WpM, b_mlp, W1, b1, (float*)d_out);
}